// Round 12
// baseline (677.091 us; speedup 1.0000x reference)
//
#include <hip/hip_runtime.h>
#include <hip/hip_bf16.h>
#include <math.h>

#define CC0 2000
#define CC1 10000
#define CC2 50000
#define DH  1024
#define BATCH 4096
#define OUT_HEAD (CC0 + 2)

#define N0_P 8192    // tail0 proj rows padded (8000 -> 8192)
#define N1_P 40192   // tail1 proj rows padded (40000 -> 40192)
#define NH_P 2048    // head rows padded (2002 -> 2048)
#define GROUP_ROWS 2048          // row-group pipelining granularity
#define T1_NBX (N1_P / 256)      // 157
#define T0_NBX (N0_P / 256)      // 32
#define GEMM_BLOCKS (8 * T0_NBX + 8 * T1_NBX)   // per group: 256 + 1256 = 1512

typedef __attribute__((ext_vector_type(4))) float  f32x4;
typedef __attribute__((ext_vector_type(8))) __bf16 bf16x8;
typedef __attribute__((ext_vector_type(8))) short  s16x8;

__device__ __forceinline__ void gload_lds16(const void* g, void* l) {
    __builtin_amdgcn_global_load_lds(
        (const __attribute__((address_space(1))) void*)g,
        (__attribute__((address_space(3))) void*)l, 16, 0, 0);
}

__device__ __forceinline__ void cvt_range(const float4* __restrict__ src,
                                          ushort4* __restrict__ dst,
                                          int ns, int nd, int start, int stride) {
    for (int i = start; i < nd; i += stride) {
        ushort4 o = {0, 0, 0, 0};
        if (i < ns) {
            float4 v = src[i];
            o.x = __builtin_bit_cast(unsigned short, (__bf16)v.x);
            o.y = __builtin_bit_cast(unsigned short, (__bf16)v.y);
            o.z = __builtin_bit_cast(unsigned short, (__bf16)v.z);
            o.w = __builtin_bit_cast(unsigned short, (__bf16)v.w);
        }
        dst[i] = o;
    }
}

// ------- small conversions: x, Wh(pad), W0a, W1a + rowsum zeroing -------
__global__ __launch_bounds__(256) void convert_small_kernel(
    const float4* __restrict__ x,   ushort4* __restrict__ x_bf,
    const float4* __restrict__ Wh,  ushort4* __restrict__ Wh_bf,
    const float4* __restrict__ W0a, ushort4* __restrict__ W0a_bf,
    const float4* __restrict__ W1a, ushort4* __restrict__ W1a_bf,
    float* __restrict__ rs0, float* __restrict__ rs1)
{
    const int start = blockIdx.x * blockDim.x + threadIdx.x;
    const int stride = gridDim.x * blockDim.x;
    switch (blockIdx.y) {
        case 0: cvt_range(x,   x_bf,   BATCH * DH / 4,    BATCH * DH / 4, start, stride); break;
        case 1: cvt_range(Wh,  Wh_bf,  OUT_HEAD * DH / 4, NH_P * DH / 4,  start, stride); break;
        case 2: cvt_range(W0a, W0a_bf, DH * DH / 4,       DH * DH / 4,    start, stride); break;
        case 3: cvt_range(W1a, W1a_bf, 256 * DH / 4,      256 * DH / 4,   start, stride); break;
        default:
            if (start < BATCH) { rs0[start] = 0.f; rs1[start] = 0.f; }
            break;
    }
}

// ------- fused: small GEMMs (h0, h1, headL) + big conversions (W0b, W1b) -------
__global__ __launch_bounds__(256) void gemm128x3_conv_kernel(
    const ushort* __restrict__ x_bf,
    const ushort* __restrict__ W0a_bf, ushort* __restrict__ h0,
    const ushort* __restrict__ W1a_bf, ushort* __restrict__ h1,
    const ushort* __restrict__ Wh_bf,  float*  __restrict__ headL,
    const float4* __restrict__ W0b,  ushort4* __restrict__ W0b_bf,
    const float4* __restrict__ W1b,  ushort4* __restrict__ W1b_bf)
{
    __shared__ ushort As[128 * 64];
    __shared__ ushort Bs[128 * 64];

    const int gb = blockIdx.x;
    if (gb >= 832) {
        // conversion segments: 512 blocks each, grid-stride
        if (gb < 1344)
            cvt_range(W0b, W0b_bf, (CC1 - CC0) * DH / 4, N0_P * DH / 4,
                      (gb - 832) * 256 + threadIdx.x, 512 * 256);
        else
            cvt_range(W1b, W1b_bf, (CC2 - CC1) * 256 / 4, N1_P * 256 / 4,
                      (gb - 1344) * 256 + threadIdx.x, 512 * 256);
        return;
    }

    const ushort* B; void* C;
    int N, ldC, wmode, nbx, lin;
    const int K = DH;
    if (gb < 256)      { B = W0a_bf; C = h0;    N = DH;       ldC = DH;       wmode = 1; nbx = 8;  lin = gb; }
    else if (gb < 320) { B = W1a_bf; C = h1;    N = 256;      ldC = 256;      wmode = 1; nbx = 2;  lin = gb - 256; }
    else               { B = Wh_bf;  C = headL; N = OUT_HEAD; ldC = OUT_HEAD; wmode = 2; nbx = 16; lin = gb - 320; }

    const int nwg = nbx * 32;
    const int q = nwg >> 3;
    int bid = (lin & 7) * q + (lin >> 3);
    const int bx = bid % nbx;
    const int by = bid / nbx;

    const int t = threadIdx.x;
    const int lane = t & 63;
    const int w = t >> 6;
    const int wr = w >> 1, wc = w & 1;
    const int lr = lane & 15;
    const int lg = lane >> 4;
    const int bm = by * 128;
    const int bn = bx * 128;
    const int lrow = lane >> 3;
    const int lcol = (lane & 7) * 8;

    f32x4 acc[4][4] = {};

    for (int k0 = 0; k0 < K; k0 += 64) {
        #pragma unroll
        for (int i = 0; i < 4; ++i) {
            const int seg = w * 4 + i;
            const int row = seg * 8 + lrow;
            gload_lds16(x_bf + (size_t)(bm + row) * K + k0 + lcol, &As[seg * 512]);
            gload_lds16(B + (size_t)(bn + row) * K + k0 + lcol, &Bs[seg * 512]);
        }
        __syncthreads();
        #pragma unroll
        for (int ks = 0; ks < 2; ++ks) {
            s16x8 af[4], bfr[4];
            #pragma unroll
            for (int m = 0; m < 4; ++m)
                af[m] = *(const s16x8*)&As[(wr * 64 + m * 16 + lr) * 64 + ks * 32 + lg * 8];
            #pragma unroll
            for (int n = 0; n < 4; ++n)
                bfr[n] = *(const s16x8*)&Bs[(wc * 64 + n * 16 + lr) * 64 + ks * 32 + lg * 8];
            #pragma unroll
            for (int m = 0; m < 4; ++m)
                #pragma unroll
                for (int n = 0; n < 4; ++n)
                    acc[m][n] = __builtin_amdgcn_mfma_f32_16x16x32_bf16(
                        __builtin_bit_cast(bf16x8, af[m]),
                        __builtin_bit_cast(bf16x8, bfr[n]), acc[m][n], 0, 0, 0);
        }
        __syncthreads();
    }

    #pragma unroll
    for (int m = 0; m < 4; ++m)
        #pragma unroll
        for (int r = 0; r < 4; ++r) {
            const int row = bm + wr * 64 + m * 16 + lg * 4 + r;
            #pragma unroll
            for (int n = 0; n < 4; ++n) {
                const int col = bn + wc * 64 + n * 16 + lr;
                float v = acc[m][n][r];
                if (col < N) {
                    if (wmode == 1)
                        ((ushort*)C)[(size_t)row * ldC + col] =
                            __builtin_bit_cast(unsigned short, (__bf16)v);
                    else
                        ((float*)C)[(size_t)row * ldC + col] = v;
                }
            }
        }
}

// ---------------- head log-softmax: one block per row ----------------
__global__ __launch_bounds__(256) void head_lsm_kernel(
    const float* __restrict__ HL, const float* __restrict__ bh,
    float* __restrict__ out, float* __restrict__ s01)
{
    const int row = blockIdx.x;
    const float* L = HL + (size_t)row * OUT_HEAD;
    const int t = threadIdx.x;
    __shared__ float red[4];

    float m = -1e30f;
    for (int i = t; i < OUT_HEAD; i += 256) m = fmaxf(m, L[i] + bh[i]);
    #pragma unroll
    for (int s = 1; s < 64; s <<= 1) m = fmaxf(m, __shfl_xor(m, s, 64));
    if ((t & 63) == 0) red[t >> 6] = m;
    __syncthreads();
    m = fmaxf(fmaxf(red[0], red[1]), fmaxf(red[2], red[3]));

    float sum = 0.f;
    for (int i = t; i < OUT_HEAD; i += 256) sum += __expf(L[i] + bh[i] - m);
    #pragma unroll
    for (int s = 1; s < 64; s <<= 1) sum += __shfl_xor(sum, s, 64);
    __syncthreads();
    if ((t & 63) == 0) red[t >> 6] = sum;
    __syncthreads();
    const float lse = m + logf(red[0] + red[1] + red[2] + red[3]);

    float* orow = out + (size_t)row * CC2;
    for (int i = t; i < CC0; i += 256) orow[i] = L[i] + bh[i] - lse;
    if (t == 0) {
        s01[2 * row + 0] = L[CC0 + 0] + bh[CC0 + 0] - lse;
        s01[2 * row + 1] = L[CC0 + 1] + bh[CC0 + 1] - lse;
    }
}

// ------- row-group tails: GEMM segment (group `ggrp`) + finalize segment ----------
// blocks [0, ngemm): 256^2 2-phase GEMM (tail0 + tail1) on rows of group ggrp
// blocks [ngemm, ngemm+nfin): finalize rows [fin_base, fin_base+nfin) (both tails)
__global__ __launch_bounds__(512, 1) void tails_pipe_kernel(
    const ushort* __restrict__ h0, const ushort* __restrict__ W0b,
    ushort* __restrict__ L0, float* __restrict__ rs0,
    const ushort* __restrict__ h1, const ushort* __restrict__ W1b,
    ushort* __restrict__ L1, float* __restrict__ rs1,
    const float* __restrict__ s01, float* __restrict__ out,
    int ggrp, int ngemm, int fin_base)
{
    __shared__ ushort lds[2][2][256 * 64];   // 128 KiB

    const int gb = blockIdx.x;
    if (gb >= ngemm) {
        // ================= finalize segment: one block per row =================
        const int row = fin_base + (gb - ngemm);
        const float a0 = s01[2 * row + 0] - logf(rs0[row]);
        const float a1 = s01[2 * row + 1] - logf(rs1[row]);
        const ushort* r0 = L0 + (size_t)row * N0_P;
        const ushort* r1 = L1 + (size_t)row * N1_P;
        float* o = out + (size_t)row * CC2;
        for (int c = threadIdx.x; c < 6000; c += 512) {
            const bool t0 = c < 1000;
            const ushort* src = t0 ? r0 + c * 8 : r1 + (c - 1000) * 8;
            float* dst = t0 ? o + CC0 + c * 8 : o + CC1 + (c - 1000) * 8;
            const float add = t0 ? a0 : a1;
            s16x8 v = *(const s16x8*)src;
            float4 o0, o1;
            o0.x = __builtin_bit_cast(float, (unsigned)(unsigned short)v[0] << 16) + add;
            o0.y = __builtin_bit_cast(float, (unsigned)(unsigned short)v[1] << 16) + add;
            o0.z = __builtin_bit_cast(float, (unsigned)(unsigned short)v[2] << 16) + add;
            o0.w = __builtin_bit_cast(float, (unsigned)(unsigned short)v[3] << 16) + add;
            o1.x = __builtin_bit_cast(float, (unsigned)(unsigned short)v[4] << 16) + add;
            o1.y = __builtin_bit_cast(float, (unsigned)(unsigned short)v[5] << 16) + add;
            o1.z = __builtin_bit_cast(float, (unsigned)(unsigned short)v[6] << 16) + add;
            o1.w = __builtin_bit_cast(float, (unsigned)(unsigned short)v[7] << 16) + add;
            *(float4*)dst = o0;
            *(float4*)(dst + 4) = o1;
        }
        return;
    }

    // ================= GEMM segment (rows ggrp*GROUP_ROWS .. +2047) =================
    const ushort *A, *B; ushort* C; float* rsum;
    int K, N, nbx, ldC, lin;
    if (gb < 8 * T0_NBX) { A = h0; B = W0b; C = L0; rsum = rs0; K = DH;  N = CC1 - CC0; nbx = T0_NBX; ldC = N0_P; lin = gb; }
    else                 { A = h1; B = W1b; C = L1; rsum = rs1; K = 256; N = CC2 - CC1; nbx = T1_NBX; ldC = N1_P; lin = gb - 8 * T0_NBX; }

    const int nwg = nbx * 8;
    const int q8 = nwg >> 3;
    int bid = (lin & 7) * q8 + (lin >> 3);
    const int by = bid % 8;       // panel-major: consecutive bids share B panel (bx)
    const int bx = bid / 8;
    const int bm = ggrp * GROUP_ROWS + by * 256, bn = bx * 256;

    const int t = threadIdx.x;
    const int lane = t & 63;
    const int w = t >> 6;        // 0..7
    const int wr = w >> 2;       // 0..1  (M half)
    const int wc = w & 3;        // 0..3  (N quarter)
    const int lr = lane & 15;
    const int lg = lane >> 4;
    const int xr = (lr & 7) << 4;          // read-side XOR (bits 4-6)
    const int c0 = w * 64 + lane;          // staging chunk id (i=0)

    f32x4 acc[8][4] = {};
    const int nkt = K / 64;

    auto stage_tile = [&](int ktile, int buf) {
        const int k0 = ktile * 64;
        #pragma unroll
        for (int h = 0; h < 4; ++h) {
            const int r0 = (h >> 1) * 128;
            const int mat = h & 1;
            const ushort* gbase = mat ? B : A;
            const int brow = mat ? bn : bm;
            #pragma unroll
            for (int i = 0; i < 2; ++i) {
                const int c = i * 512 + c0;
                const int rl = c >> 3;
                const int cc = (c & 7) ^ (rl & 7);
                gload_lds16(gbase + (size_t)(brow + r0 + rl) * K + k0 + cc * 8,
                            (char*)&lds[buf][mat][0] + r0 * 128 + (i * 512 + w * 64) * 16);
            }
        }
    };

    stage_tile(0, 0);
    asm volatile("s_waitcnt vmcnt(0)");
    __builtin_amdgcn_s_barrier();
    asm volatile("" ::: "memory");

    for (int tk = 0; tk < nkt; ++tk) {
        const int cur = tk & 1;
        if (tk + 1 < nkt) stage_tile(tk + 1, cur ^ 1);   // issue early, wait late
        const char* baseA = (const char*)&lds[cur][0][0];
        const char* baseB = (const char*)&lds[cur][1][0];

        s16x8 bfr[4][2];
        #pragma unroll
        for (int n_ = 0; n_ < 4; ++n_) {
            const int row = wc * 64 + n_ * 16 + lr;
            #pragma unroll
            for (int ks = 0; ks < 2; ++ks)
                bfr[n_][ks] = *(const s16x8*)(baseB + (row * 128 + ((ks * 64 + lg * 16) ^ xr)));
        }
        #pragma unroll
        for (int mh = 0; mh < 2; ++mh) {
            s16x8 af[4][2];
            #pragma unroll
            for (int m_ = 0; m_ < 4; ++m_) {
                const int row = wr * 128 + (mh * 4 + m_) * 16 + lr;
                #pragma unroll
                for (int ks = 0; ks < 2; ++ks)
                    af[m_][ks] = *(const s16x8*)(baseA + (row * 128 + ((ks * 64 + lg * 16) ^ xr)));
            }
            __builtin_amdgcn_s_setprio(1);
            #pragma unroll
            for (int m_ = 0; m_ < 4; ++m_)
                #pragma unroll
                for (int n_ = 0; n_ < 4; ++n_)
                    #pragma unroll
                    for (int ks = 0; ks < 2; ++ks)
                        acc[mh * 4 + m_][n_] = __builtin_amdgcn_mfma_f32_16x16x32_bf16(
                            __builtin_bit_cast(bf16x8, af[m_][ks]),
                            __builtin_bit_cast(bf16x8, bfr[n_][ks]),
                            acc[mh * 4 + m_][n_], 0, 0, 0);
            __builtin_amdgcn_s_setprio(0);
        }
        asm volatile("s_waitcnt vmcnt(0)" ::: "memory");
        __builtin_amdgcn_s_barrier();
        asm volatile("" ::: "memory");
    }

    // epilogue: bf16 store + fused sum-of-exp
    #pragma unroll
    for (int m = 0; m < 8; ++m) {
        #pragma unroll
        for (int r = 0; r < 4; ++r) {
            const int row = bm + wr * 128 + m * 16 + lg * 4 + r;
            float psum = 0.f;
            #pragma unroll
            for (int n = 0; n < 4; ++n) {
                const int col = bn + wc * 64 + n * 16 + lr;
                float v = acc[m][n][r];
                if (col < N) {
                    C[(size_t)row * ldC + col] =
                        __builtin_bit_cast(unsigned short, (__bf16)v);
                    psum += __expf(v);   // logits O(1): max-free LSE safe
                }
            }
            #pragma unroll
            for (int mm = 1; mm < 16; mm <<= 1) psum += __shfl_xor(psum, mm, 64);
            if (lr == 0) atomicAdd(&rsum[row], psum);
        }
    }
}

// ---------------- launch ----------------
extern "C" void kernel_launch(void* const* d_in, const int* in_sizes, int n_in,
                              void* d_out, int out_size, void* d_ws, size_t ws_size,
                              hipStream_t stream) {
    const float* x   = (const float*)d_in[0];
    const float* Wh  = (const float*)d_in[1];
    const float* bh  = (const float*)d_in[2];
    const float* W0a = (const float*)d_in[3];
    const float* W0b = (const float*)d_in[4];
    const float* W1a = (const float*)d_in[5];
    const float* W1b = (const float*)d_in[6];
    float* out = (float*)d_out;
    char*  ws  = (char*)d_ws;

    size_t off = 0;
    auto alloc = [&](size_t bytes) { size_t o = off; off += (bytes + 255) & ~(size_t)255; return o; };
    ushort* x_bf   = (ushort*)(ws + alloc((size_t)BATCH * DH * 2));
    ushort* Wh_bf  = (ushort*)(ws + alloc((size_t)NH_P * DH * 2));
    ushort* W0a_bf = (ushort*)(ws + alloc((size_t)DH * DH * 2));
    ushort* W0b_bf = (ushort*)(ws + alloc((size_t)N0_P * DH * 2));
    ushort* W1a_bf = (ushort*)(ws + alloc((size_t)256 * DH * 2));
    ushort* W1b_bf = (ushort*)(ws + alloc((size_t)N1_P * 256 * 2));
    ushort* h0_bf  = (ushort*)(ws + alloc((size_t)BATCH * DH * 2));
    ushort* h1_bf  = (ushort*)(ws + alloc((size_t)BATCH * 256 * 2));
    float*  headL  = (float*)(ws + alloc((size_t)BATCH * OUT_HEAD * 4));
    float*  s01    = (float*)(ws + alloc((size_t)BATCH * 2 * 4));
    float*  rs0    = (float*)(ws + alloc((size_t)BATCH * 4));
    float*  rs1    = (float*)(ws + alloc((size_t)BATCH * 4));
    ushort* L0     = (ushort*)(ws + alloc((size_t)BATCH * N0_P * 2));
    ushort* L1     = (ushort*)(ws + alloc((size_t)BATCH * N1_P * 2));

    // 1) small conversions + rowsum zero
    convert_small_kernel<<<dim3(1024, 5), 256, 0, stream>>>(
        (const float4*)x,   (ushort4*)x_bf,
        (const float4*)Wh,  (ushort4*)Wh_bf,
        (const float4*)W0a, (ushort4*)W0a_bf,
        (const float4*)W1a, (ushort4*)W1a_bf,
        rs0, rs1);

    // 2) producers (832 GEMM blocks) + big conversions (1024 blocks)
    gemm128x3_conv_kernel<<<1856, 256, 0, stream>>>(
        x_bf, W0a_bf, h0_bf, W1a_bf, h1_bf, Wh_bf, headL,
        (const float4*)W0b, (ushort4*)W0b_bf,
        (const float4*)W1b, (ushort4*)W1b_bf);

    // 3) head log-softmax -> out[:, :2000] + cluster scalars
    head_lsm_kernel<<<BATCH, 256, 0, stream>>>(headL, bh, out, s01);

    // 4) GEMM group 0
    tails_pipe_kernel<<<GEMM_BLOCKS, 512, 0, stream>>>(
        h0_bf, W0b_bf, L0, rs0, h1_bf, W1b_bf, L1, rs1, s01, out,
        0, GEMM_BLOCKS, 0);
    // 5) GEMM group 1 + finalize group 0 (overlapped)
    tails_pipe_kernel<<<GEMM_BLOCKS + GROUP_ROWS, 512, 0, stream>>>(
        h0_bf, W0b_bf, L0, rs0, h1_bf, W1b_bf, L1, rs1, s01, out,
        1, GEMM_BLOCKS, 0);
    // 6) finalize group 1
    tails_pipe_kernel<<<GROUP_ROWS, 512, 0, stream>>>(
        h0_bf, W0b_bf, L0, rs0, h1_bf, W1b_bf, L1, rs1, s01, out,
        0, 0, GROUP_ROWS);
}

// Round 13
// 606.142 us; speedup vs baseline: 1.1170x; 1.1170x over previous
//
#include <hip/hip_runtime.h>
#include <hip/hip_bf16.h>
#include <math.h>

#define CC0 2000
#define CC1 10000
#define CC2 50000
#define DH  1024
#define BATCH 4096
#define OUT_HEAD (CC0 + 2)

#define N0_P 8192    // tail0 proj rows padded (8000 -> 8192)
#define N1_P 40192   // tail1 proj rows padded (40000 -> 40192)
#define NH_P 2048    // head rows padded (2002 -> 2048)

typedef __attribute__((ext_vector_type(4))) float  f32x4;
typedef __attribute__((ext_vector_type(8))) __bf16 bf16x8;
typedef __attribute__((ext_vector_type(8))) short  s16x8;

__device__ __forceinline__ void gload_lds16(const void* g, void* l) {
    __builtin_amdgcn_global_load_lds(
        (const __attribute__((address_space(1))) void*)g,
        (__attribute__((address_space(3))) void*)l, 16, 0, 0);
}

// ------- fp32 -> bf16 conversions (6 segments) + rowsum zeroing (segment 6) -------
__global__ __launch_bounds__(256) void convert_all_kernel(
    const float4* __restrict__ s0, ushort4* __restrict__ d0, int n0s, int n0d,
    const float4* __restrict__ s1, ushort4* __restrict__ d1, int n1s, int n1d,
    const float4* __restrict__ s2, ushort4* __restrict__ d2, int n2s, int n2d,
    const float4* __restrict__ s3, ushort4* __restrict__ d3, int n3s, int n3d,
    const float4* __restrict__ s4, ushort4* __restrict__ d4, int n4s, int n4d,
    const float4* __restrict__ s5, ushort4* __restrict__ d5, int n5s, int n5d,
    float* __restrict__ rs0, float* __restrict__ rs1)
{
    if (blockIdx.y == 6) {
        int i = blockIdx.x * blockDim.x + threadIdx.x;
        if (i < BATCH) { rs0[i] = 0.f; rs1[i] = 0.f; }
        return;
    }
    const float4* src; ushort4* dst; int ns, nd;
    switch (blockIdx.y) {
        case 0: src = s0; dst = d0; ns = n0s; nd = n0d; break;
        case 1: src = s1; dst = d1; ns = n1s; nd = n1d; break;
        case 2: src = s2; dst = d2; ns = n2s; nd = n2d; break;
        case 3: src = s3; dst = d3; ns = n3s; nd = n3d; break;
        case 4: src = s4; dst = d4; ns = n4s; nd = n4d; break;
        default: src = s5; dst = d5; ns = n5s; nd = n5d; break;
    }
    int i = blockIdx.x * blockDim.x + threadIdx.x;
    const int stride = gridDim.x * blockDim.x;
    for (; i < nd; i += stride) {
        ushort4 o = {0, 0, 0, 0};
        if (i < ns) {
            float4 v = src[i];
            o.x = __builtin_bit_cast(unsigned short, (__bf16)v.x);
            o.y = __builtin_bit_cast(unsigned short, (__bf16)v.y);
            o.z = __builtin_bit_cast(unsigned short, (__bf16)v.z);
            o.w = __builtin_bit_cast(unsigned short, (__bf16)v.w);
        }
        dst[i] = o;
    }
}

// ------- fused small GEMMs (m97 128^2): h0 = x@W0a^T, h1 = x@W1a^T (bf16), headL = x@Wh^T (f32)
__global__ __launch_bounds__(256) void gemm128x3_kernel(
    const ushort* __restrict__ x_bf,
    const ushort* __restrict__ W0a_bf, ushort* __restrict__ h0,
    const ushort* __restrict__ W1a_bf, ushort* __restrict__ h1,
    const ushort* __restrict__ Wh_bf,  float*  __restrict__ headL)
{
    __shared__ ushort As[128 * 64];
    __shared__ ushort Bs[128 * 64];

    const int gb = blockIdx.x;
    const ushort* B; void* C;
    int N, ldC, wmode, nbx, lin;
    const int K = DH;
    if (gb < 256)      { B = W0a_bf; C = h0;    N = DH;       ldC = DH;       wmode = 1; nbx = 8;  lin = gb; }
    else if (gb < 320) { B = W1a_bf; C = h1;    N = 256;      ldC = 256;      wmode = 1; nbx = 2;  lin = gb - 256; }
    else               { B = Wh_bf;  C = headL; N = OUT_HEAD; ldC = OUT_HEAD; wmode = 2; nbx = 16; lin = gb - 320; }

    const int nwg = nbx * 32;
    const int q = nwg >> 3;
    int bid = (lin & 7) * q + (lin >> 3);
    const int bx = bid % nbx;
    const int by = bid / nbx;

    const int t = threadIdx.x;
    const int lane = t & 63;
    const int w = t >> 6;
    const int wr = w >> 1, wc = w & 1;
    const int lr = lane & 15;
    const int lg = lane >> 4;
    const int bm = by * 128;
    const int bn = bx * 128;
    const int lrow = lane >> 3;
    const int lcol = (lane & 7) * 8;

    f32x4 acc[4][4] = {};

    for (int k0 = 0; k0 < K; k0 += 64) {
        #pragma unroll
        for (int i = 0; i < 4; ++i) {
            const int seg = w * 4 + i;
            const int row = seg * 8 + lrow;
            gload_lds16(x_bf + (size_t)(bm + row) * K + k0 + lcol, &As[seg * 512]);
            gload_lds16(B + (size_t)(bn + row) * K + k0 + lcol, &Bs[seg * 512]);
        }
        __syncthreads();
        #pragma unroll
        for (int ks = 0; ks < 2; ++ks) {
            s16x8 af[4], bfr[4];
            #pragma unroll
            for (int m = 0; m < 4; ++m)
                af[m] = *(const s16x8*)&As[(wr * 64 + m * 16 + lr) * 64 + ks * 32 + lg * 8];
            #pragma unroll
            for (int n = 0; n < 4; ++n)
                bfr[n] = *(const s16x8*)&Bs[(wc * 64 + n * 16 + lr) * 64 + ks * 32 + lg * 8];
            #pragma unroll
            for (int m = 0; m < 4; ++m)
                #pragma unroll
                for (int n = 0; n < 4; ++n)
                    acc[m][n] = __builtin_amdgcn_mfma_f32_16x16x32_bf16(
                        __builtin_bit_cast(bf16x8, af[m]),
                        __builtin_bit_cast(bf16x8, bfr[n]), acc[m][n], 0, 0, 0);
        }
        __syncthreads();
    }

    #pragma unroll
    for (int m = 0; m < 4; ++m)
        #pragma unroll
        for (int r = 0; r < 4; ++r) {
            const int row = bm + wr * 64 + m * 16 + lg * 4 + r;
            #pragma unroll
            for (int n = 0; n < 4; ++n) {
                const int col = bn + wc * 64 + n * 16 + lr;
                float v = acc[m][n][r];
                if (col < N) {
                    if (wmode == 1)
                        ((ushort*)C)[(size_t)row * ldC + col] =
                            __builtin_bit_cast(unsigned short, (__bf16)v);
                    else
                        ((float*)C)[(size_t)row * ldC + col] = v;
                }
            }
        }
}

// ------- fused tail GEMMs: 256^2 tile, 4-phase counted-vmcnt schedule (T3+T4+T5) ----
// seg0 (512 blocks):  L0 = h0 @ W0b^T (bf16) + rowsum rs0   (K=1024)
// seg1 (2512 blocks): L1 = h1 @ W1b^T (bf16) + rowsum rs1   (K=256)
// Per K-tile: 4 phases, one C-quadrant (mh,nh) each.  Chunk staging order
// [A0,B0,B1,A1] matches first-use order; every phase: issue 1 chunk of tile t+1
// (2 gload_lds), s_waitcnt vmcnt(6) (3 chunks in flight), 1 barrier, 12 ds_read,
// 16 MFMA (setprio-wrapped).  Last tile drains 4->2->0.  LDS layout and
// read-side XOR swizzle identical to the validated 2-phase kernel.
__global__ __launch_bounds__(512, 1) void tails256_kernel(
    const ushort* __restrict__ h0, const ushort* __restrict__ W0b,
    ushort* __restrict__ L0, float* __restrict__ rs0,
    const ushort* __restrict__ h1, const ushort* __restrict__ W1b,
    ushort* __restrict__ L1, float* __restrict__ rs1)
{
    __shared__ ushort lds[2][2][256 * 64];   // 128 KiB

    const int gb = blockIdx.x;
    const ushort *A, *B; ushort* C; float* rsum;
    int K, N, nbx, ldC, lin;
    if (gb < 512) { A = h0; B = W0b; C = L0; rsum = rs0; K = DH;  N = CC1 - CC0; nbx = N0_P / 256; ldC = N0_P; lin = gb; }
    else          { A = h1; B = W1b; C = L1; rsum = rs1; K = 256; N = CC2 - CC1; nbx = N1_P / 256; ldC = N1_P; lin = gb - 512; }

    const int nwg = nbx * 16;
    const int q8 = nwg >> 3;
    int bid = (lin & 7) * q8 + (lin >> 3);
    const int by = bid % 16;      // panel-major: consecutive bids share B panel (bx)
    const int bx = bid / 16;
    const int bm = by * 256, bn = bx * 256;

    const int t = threadIdx.x;
    const int lane = t & 63;
    const int w = t >> 6;        // 0..7
    const int wr = w >> 2;       // 0..1  (M half)
    const int wc = w & 3;        // 0..3  (N quarter)
    const int lr = lane & 15;
    const int lg = lane >> 4;
    const int xr = (lr & 7) << 4;          // read-side XOR (bits 4-6)
    const int c0 = w * 64 + lane;          // staging lane id

    f32x4 acc[8][4] = {};
    const int nkt = K / 64;

    // stage chunk p of K-tile `ktile` into buffer `buf`.
    // p: 0 -> A rows {0-63,128-191}; 1 -> B rows {0-31,64-95,128-159,192-223};
    //    2 -> B rows {32-63,96-127,160-191,224-255}; 3 -> A rows {64-127,192-255}
    auto stage_chunk = [&](int ktile, int buf, int p) {
        const int k0 = ktile * 64;
        const int mat = (p == 1 || p == 2) ? 1 : 0;
        const int j = p >> 1;                 // A: quarter-pair sel; B: slice sel
        const ushort* gbase = mat ? B : A;
        const int brow = mat ? bn : bm;
        #pragma unroll
        for (int i = 0; i < 2; ++i) {
            const int v = i * 512 + c0;       // per-lane virtual index
            const int vrow = v >> 3;          // 0..127 virtual row
            int ar;                           // actual LDS/global row
            if (mat == 0) ar = ((vrow >> 6) << 7) + (j << 6) + (vrow & 63);
            else          ar = ((vrow >> 5) << 6) + (j << 5) + (vrow & 31);
            const int cc = (v & 7) ^ (ar & 7);   // pre-swizzled source col chunk
            const int v0 = (i * 512 + w * 64) >> 3;  // wave-uniform start vrow
            int ar0;
            if (mat == 0) ar0 = ((v0 >> 6) << 7) + (j << 6) + (v0 & 63);
            else          ar0 = ((v0 >> 5) << 6) + (j << 5) + (v0 & 31);
            gload_lds16(gbase + (size_t)(brow + ar) * K + k0 + cc * 8,
                        (char*)&lds[buf][mat][0] + ar0 * 128);
        }
    };

    // ---- prologue: stage tile 0 fully, drain once
    #pragma unroll
    for (int p = 0; p < 4; ++p) stage_chunk(0, 0, p);
    asm volatile("s_waitcnt vmcnt(0)" ::: "memory");
    __builtin_amdgcn_s_barrier();
    asm volatile("" ::: "memory");

    for (int tk = 0; tk < nkt; ++tk) {
        const int cur = tk & 1;
        const char* baseA = (const char*)&lds[cur][0][0];
        const char* baseB = (const char*)&lds[cur][1][0];
        const bool more = (tk + 1 < nkt);
        #pragma unroll
        for (int p = 0; p < 4; ++p) {
            const int mh = p >> 1, nh = p & 1;
            // issue chunk p of next tile into the other buffer
            if (more) {
                stage_chunk(tk + 1, cur ^ 1, p);
                asm volatile("s_waitcnt vmcnt(6)" ::: "memory");
            } else {
                if (p == 0)      asm volatile("s_waitcnt vmcnt(4)" ::: "memory");
                else if (p == 1) asm volatile("s_waitcnt vmcnt(2)" ::: "memory");
                else if (p == 2) asm volatile("s_waitcnt vmcnt(0)" ::: "memory");
            }
            __builtin_amdgcn_s_barrier();
            asm volatile("" ::: "memory");

            // 12 ds_read_b128: quadrant fragments
            s16x8 af[4][2], bq[2][2];
            #pragma unroll
            for (int m_ = 0; m_ < 4; ++m_) {
                const int row = wr * 128 + (mh * 4 + m_) * 16 + lr;
                #pragma unroll
                for (int ks = 0; ks < 2; ++ks)
                    af[m_][ks] = *(const s16x8*)(baseA + (row * 128 + ((ks * 64 + lg * 16) ^ xr)));
            }
            #pragma unroll
            for (int n_ = 0; n_ < 2; ++n_) {
                const int row = wc * 64 + (nh * 2 + n_) * 16 + lr;
                #pragma unroll
                for (int ks = 0; ks < 2; ++ks)
                    bq[n_][ks] = *(const s16x8*)(baseB + (row * 128 + ((ks * 64 + lg * 16) ^ xr)));
            }
            __builtin_amdgcn_s_setprio(1);
            #pragma unroll
            for (int m_ = 0; m_ < 4; ++m_)
                #pragma unroll
                for (int n_ = 0; n_ < 2; ++n_)
                    #pragma unroll
                    for (int ks = 0; ks < 2; ++ks)
                        acc[mh * 4 + m_][nh * 2 + n_] = __builtin_amdgcn_mfma_f32_16x16x32_bf16(
                            __builtin_bit_cast(bf16x8, af[m_][ks]),
                            __builtin_bit_cast(bf16x8, bq[n_][ks]),
                            acc[mh * 4 + m_][nh * 2 + n_], 0, 0, 0);
            __builtin_amdgcn_s_setprio(0);
        }
    }

    // ---- epilogue: bf16 store + fused sum-of-exp
    #pragma unroll
    for (int m = 0; m < 8; ++m) {
        #pragma unroll
        for (int r = 0; r < 4; ++r) {
            const int row = bm + wr * 128 + m * 16 + lg * 4 + r;
            float psum = 0.f;
            #pragma unroll
            for (int n = 0; n < 4; ++n) {
                const int col = bn + wc * 64 + n * 16 + lr;
                float v = acc[m][n][r];
                if (col < N) {
                    C[(size_t)row * ldC + col] =
                        __builtin_bit_cast(unsigned short, (__bf16)v);
                    psum += __expf(v);   // logits O(1): max-free LSE safe
                }
            }
            #pragma unroll
            for (int mm = 1; mm < 16; mm <<= 1) psum += __shfl_xor(psum, mm, 64);
            if (lr == 0) atomicAdd(&rsum[row], psum);
        }
    }
}

// ---------------- head log-softmax: one block per row ----------------
__global__ __launch_bounds__(256) void head_lsm_kernel(
    const float* __restrict__ HL, const float* __restrict__ bh,
    float* __restrict__ out, float* __restrict__ s01)
{
    const int row = blockIdx.x;
    const float* L = HL + (size_t)row * OUT_HEAD;
    const int t = threadIdx.x;
    __shared__ float red[4];

    float m = -1e30f;
    for (int i = t; i < OUT_HEAD; i += 256) m = fmaxf(m, L[i] + bh[i]);
    #pragma unroll
    for (int s = 1; s < 64; s <<= 1) m = fmaxf(m, __shfl_xor(m, s, 64));
    if ((t & 63) == 0) red[t >> 6] = m;
    __syncthreads();
    m = fmaxf(fmaxf(red[0], red[1]), fmaxf(red[2], red[3]));

    float sum = 0.f;
    for (int i = t; i < OUT_HEAD; i += 256) sum += __expf(L[i] + bh[i] - m);
    #pragma unroll
    for (int s = 1; s < 64; s <<= 1) sum += __shfl_xor(sum, s, 64);
    __syncthreads();
    if ((t & 63) == 0) red[t >> 6] = sum;
    __syncthreads();
    const float lse = m + logf(red[0] + red[1] + red[2] + red[3]);

    float* orow = out + (size_t)row * CC2;
    for (int i = t; i < CC0; i += 256) orow[i] = L[i] + bh[i] - lse;
    if (t == 0) {
        s01[2 * row + 0] = L[CC0 + 0] + bh[CC0 + 0] - lse;
        s01[2 * row + 1] = L[CC0 + 1] + bh[CC0 + 1] - lse;
    }
}

// ---------------- per-row additive constants: add = s01 - log(rowsum) ----------------
__global__ __launch_bounds__(256) void prep_add_kernel(
    const float* __restrict__ s01, const float* __restrict__ rs0,
    const float* __restrict__ rs1, float* __restrict__ add0,
    float* __restrict__ add1, int n)
{
    int i = blockIdx.x * blockDim.x + threadIdx.x;
    if (i < n) {
        add0[i] = s01[2 * i + 0] - logf(rs0[i]);
        add1[i] = s01[2 * i + 1] - logf(rs1[i]);
    }
}

// ------- fused finalize: both tails, bf16 logits -> fp32 out + add[row] -------------
__global__ __launch_bounds__(256) void finalize_all_kernel(
    const ushort* __restrict__ L0, const ushort* __restrict__ L1,
    const float* __restrict__ add0, const float* __restrict__ add1,
    float* __restrict__ out)
{
    const int row = blockIdx.y;
    const int c = blockIdx.x * blockDim.x + threadIdx.x;
    const ushort* src; float* dst; float add;
    if (c < 1000) {
        src = L0 + (size_t)row * N0_P + c * 8;
        dst = out + (size_t)row * CC2 + CC0 + c * 8;
        add = add0[row];
    } else if (c < 6000) {
        const int c1 = c - 1000;
        src = L1 + (size_t)row * N1_P + c1 * 8;
        dst = out + (size_t)row * CC2 + CC1 + c1 * 8;
        add = add1[row];
    } else return;
    s16x8 v = *(const s16x8*)src;
    float4 o0, o1;
    o0.x = __builtin_bit_cast(float, (unsigned)(unsigned short)v[0] << 16) + add;
    o0.y = __builtin_bit_cast(float, (unsigned)(unsigned short)v[1] << 16) + add;
    o0.z = __builtin_bit_cast(float, (unsigned)(unsigned short)v[2] << 16) + add;
    o0.w = __builtin_bit_cast(float, (unsigned)(unsigned short)v[3] << 16) + add;
    o1.x = __builtin_bit_cast(float, (unsigned)(unsigned short)v[4] << 16) + add;
    o1.y = __builtin_bit_cast(float, (unsigned)(unsigned short)v[5] << 16) + add;
    o1.z = __builtin_bit_cast(float, (unsigned)(unsigned short)v[6] << 16) + add;
    o1.w = __builtin_bit_cast(float, (unsigned)(unsigned short)v[7] << 16) + add;
    *(float4*)dst = o0;
    *(float4*)(dst + 4) = o1;
}

// ---------------- launch ----------------
extern "C" void kernel_launch(void* const* d_in, const int* in_sizes, int n_in,
                              void* d_out, int out_size, void* d_ws, size_t ws_size,
                              hipStream_t stream) {
    const float* x   = (const float*)d_in[0];
    const float* Wh  = (const float*)d_in[1];
    const float* bh  = (const float*)d_in[2];
    const float* W0a = (const float*)d_in[3];
    const float* W0b = (const float*)d_in[4];
    const float* W1a = (const float*)d_in[5];
    const float* W1b = (const float*)d_in[6];
    float* out = (float*)d_out;
    char*  ws  = (char*)d_ws;

    size_t off = 0;
    auto alloc = [&](size_t bytes) { size_t o = off; off += (bytes + 255) & ~(size_t)255; return o; };
    ushort* x_bf   = (ushort*)(ws + alloc((size_t)BATCH * DH * 2));
    ushort* Wh_bf  = (ushort*)(ws + alloc((size_t)NH_P * DH * 2));
    ushort* W0a_bf = (ushort*)(ws + alloc((size_t)DH * DH * 2));
    ushort* W0b_bf = (ushort*)(ws + alloc((size_t)N0_P * DH * 2));
    ushort* W1a_bf = (ushort*)(ws + alloc((size_t)256 * DH * 2));
    ushort* W1b_bf = (ushort*)(ws + alloc((size_t)N1_P * 256 * 2));
    ushort* h0_bf  = (ushort*)(ws + alloc((size_t)BATCH * DH * 2));
    ushort* h1_bf  = (ushort*)(ws + alloc((size_t)BATCH * 256 * 2));
    float*  headL  = (float*)(ws + alloc((size_t)BATCH * OUT_HEAD * 4));
    float*  s01    = (float*)(ws + alloc((size_t)BATCH * 2 * 4));
    float*  rs0    = (float*)(ws + alloc((size_t)BATCH * 4));
    float*  rs1    = (float*)(ws + alloc((size_t)BATCH * 4));
    float*  add0   = (float*)(ws + alloc((size_t)BATCH * 4));
    float*  add1   = (float*)(ws + alloc((size_t)BATCH * 4));
    ushort* L0     = (ushort*)(ws + alloc((size_t)BATCH * N0_P * 2));
    ushort* L1     = (ushort*)(ws + alloc((size_t)BATCH * N1_P * 2));

    convert_all_kernel<<<dim3(1280, 7), 256, 0, stream>>>(
        (const float4*)x,   (ushort4*)x_bf,   BATCH * DH / 4,        BATCH * DH / 4,
        (const float4*)Wh,  (ushort4*)Wh_bf,  OUT_HEAD * DH / 4,     NH_P * DH / 4,
        (const float4*)W0a, (ushort4*)W0a_bf, DH * DH / 4,           DH * DH / 4,
        (const float4*)W0b, (ushort4*)W0b_bf, (CC1 - CC0) * DH / 4,  N0_P * DH / 4,
        (const float4*)W1a, (ushort4*)W1a_bf, 256 * DH / 4,          256 * DH / 4,
        (const float4*)W1b, (ushort4*)W1b_bf, (CC2 - CC1) * 256 / 4, N1_P * 256 / 4,
        rs0, rs1);

    // producers: h0 (256 blocks) + h1 (64) + head (512)
    gemm128x3_kernel<<<832, 256, 0, stream>>>(
        x_bf, W0a_bf, h0_bf, W1a_bf, h1_bf, Wh_bf, headL);

    // head log-softmax -> out[:, :2000] + cluster scalars
    head_lsm_kernel<<<BATCH, 256, 0, stream>>>(headL, bh, out, s01);

    // fused tails (single GEMM pass each, 4-phase counted-vmcnt): bf16 logits + rowsums
    tails256_kernel<<<512 + (N1_P / 256) * 16, 512, 0, stream>>>(
        h0_bf, W0b_bf, L0, rs0, h1_bf, W1b_bf, L1, rs1);

    // per-row additive constants
    prep_add_kernel<<<(BATCH + 255) / 256, 256, 0, stream>>>(s01, rs0, rs1, add0, add1, BATCH);

    // fused finalize: both tails -> fp32 out
    finalize_all_kernel<<<dim3(24, BATCH), 256, 0, stream>>>(L0, L1, add0, add1, out);
}

// Round 14
// 600.417 us; speedup vs baseline: 1.1277x; 1.0095x over previous
//
#include <hip/hip_runtime.h>
#include <hip/hip_bf16.h>
#include <math.h>

#define CC0 2000
#define CC1 10000
#define CC2 50000
#define DH  1024
#define BATCH 4096
#define OUT_HEAD (CC0 + 2)

#define N0_P 8192    // tail0 proj rows padded (8000 -> 8192)
#define N1_P 40192   // tail1 proj rows padded (40000 -> 40192)
#define NH_P 2048    // head rows padded (2002 -> 2048)

typedef __attribute__((ext_vector_type(4))) float  f32x4;
typedef __attribute__((ext_vector_type(8))) __bf16 bf16x8;
typedef __attribute__((ext_vector_type(8))) short  s16x8;

__device__ __forceinline__ void gload_lds16(const void* g, void* l) {
    __builtin_amdgcn_global_load_lds(
        (const __attribute__((address_space(1))) void*)g,
        (__attribute__((address_space(3))) void*)l, 16, 0, 0);
}

// ------- fp32 -> bf16 conversions (6 segments) -------
__global__ __launch_bounds__(256) void convert_all_kernel(
    const float4* __restrict__ s0, ushort4* __restrict__ d0, int n0s, int n0d,
    const float4* __restrict__ s1, ushort4* __restrict__ d1, int n1s, int n1d,
    const float4* __restrict__ s2, ushort4* __restrict__ d2, int n2s, int n2d,
    const float4* __restrict__ s3, ushort4* __restrict__ d3, int n3s, int n3d,
    const float4* __restrict__ s4, ushort4* __restrict__ d4, int n4s, int n4d,
    const float4* __restrict__ s5, ushort4* __restrict__ d5, int n5s, int n5d)
{
    const float4* src; ushort4* dst; int ns, nd;
    switch (blockIdx.y) {
        case 0: src = s0; dst = d0; ns = n0s; nd = n0d; break;
        case 1: src = s1; dst = d1; ns = n1s; nd = n1d; break;
        case 2: src = s2; dst = d2; ns = n2s; nd = n2d; break;
        case 3: src = s3; dst = d3; ns = n3s; nd = n3d; break;
        case 4: src = s4; dst = d4; ns = n4s; nd = n4d; break;
        default: src = s5; dst = d5; ns = n5s; nd = n5d; break;
    }
    int i = blockIdx.x * blockDim.x + threadIdx.x;
    const int stride = gridDim.x * blockDim.x;
    for (; i < nd; i += stride) {
        ushort4 o = {0, 0, 0, 0};
        if (i < ns) {
            float4 v = src[i];
            o.x = __builtin_bit_cast(unsigned short, (__bf16)v.x);
            o.y = __builtin_bit_cast(unsigned short, (__bf16)v.y);
            o.z = __builtin_bit_cast(unsigned short, (__bf16)v.z);
            o.w = __builtin_bit_cast(unsigned short, (__bf16)v.w);
        }
        dst[i] = o;
    }
}

// ------- fused small GEMMs (m97 128^2): h0 = x@W0a^T, h1 = x@W1a^T (bf16), headL = x@Wh^T (f32)
__global__ __launch_bounds__(256) void gemm128x3_kernel(
    const ushort* __restrict__ x_bf,
    const ushort* __restrict__ W0a_bf, ushort* __restrict__ h0,
    const ushort* __restrict__ W1a_bf, ushort* __restrict__ h1,
    const ushort* __restrict__ Wh_bf,  float*  __restrict__ headL)
{
    __shared__ ushort As[128 * 64];
    __shared__ ushort Bs[128 * 64];

    const int gb = blockIdx.x;
    const ushort* B; void* C;
    int N, ldC, wmode, nbx, lin;
    const int K = DH;
    if (gb < 256)      { B = W0a_bf; C = h0;    N = DH;       ldC = DH;       wmode = 1; nbx = 8;  lin = gb; }
    else if (gb < 320) { B = W1a_bf; C = h1;    N = 256;      ldC = 256;      wmode = 1; nbx = 2;  lin = gb - 256; }
    else               { B = Wh_bf;  C = headL; N = OUT_HEAD; ldC = OUT_HEAD; wmode = 2; nbx = 16; lin = gb - 320; }

    const int nwg = nbx * 32;
    const int q = nwg >> 3;
    int bid = (lin & 7) * q + (lin >> 3);
    const int bx = bid % nbx;
    const int by = bid / nbx;

    const int t = threadIdx.x;
    const int lane = t & 63;
    const int w = t >> 6;
    const int wr = w >> 1, wc = w & 1;
    const int lr = lane & 15;
    const int lg = lane >> 4;
    const int bm = by * 128;
    const int bn = bx * 128;
    const int lrow = lane >> 3;
    const int lcol = (lane & 7) * 8;

    f32x4 acc[4][4] = {};

    for (int k0 = 0; k0 < K; k0 += 64) {
        #pragma unroll
        for (int i = 0; i < 4; ++i) {
            const int seg = w * 4 + i;
            const int row = seg * 8 + lrow;
            gload_lds16(x_bf + (size_t)(bm + row) * K + k0 + lcol, &As[seg * 512]);
            gload_lds16(B + (size_t)(bn + row) * K + k0 + lcol, &Bs[seg * 512]);
        }
        __syncthreads();
        #pragma unroll
        for (int ks = 0; ks < 2; ++ks) {
            s16x8 af[4], bfr[4];
            #pragma unroll
            for (int m = 0; m < 4; ++m)
                af[m] = *(const s16x8*)&As[(wr * 64 + m * 16 + lr) * 64 + ks * 32 + lg * 8];
            #pragma unroll
            for (int n = 0; n < 4; ++n)
                bfr[n] = *(const s16x8*)&Bs[(wc * 64 + n * 16 + lr) * 64 + ks * 32 + lg * 8];
            #pragma unroll
            for (int m = 0; m < 4; ++m)
                #pragma unroll
                for (int n = 0; n < 4; ++n)
                    acc[m][n] = __builtin_amdgcn_mfma_f32_16x16x32_bf16(
                        __builtin_bit_cast(bf16x8, af[m]),
                        __builtin_bit_cast(bf16x8, bfr[n]), acc[m][n], 0, 0, 0);
        }
        __syncthreads();
    }

    #pragma unroll
    for (int m = 0; m < 4; ++m)
        #pragma unroll
        for (int r = 0; r < 4; ++r) {
            const int row = bm + wr * 64 + m * 16 + lg * 4 + r;
            #pragma unroll
            for (int n = 0; n < 4; ++n) {
                const int col = bn + wc * 64 + n * 16 + lr;
                float v = acc[m][n][r];
                if (col < N) {
                    if (wmode == 1)
                        ((ushort*)C)[(size_t)row * ldC + col] =
                            __builtin_bit_cast(unsigned short, (__bf16)v);
                    else
                        ((float*)C)[(size_t)row * ldC + col] = v;
                }
            }
        }
}

// ------- fused tail GEMMs: 256^2 tile, 4-phase counted-vmcnt, minimal ds_reads -----
// seg0 (512 blocks):  L0 = h0 @ W0b^T (bf16)   (K=1024)
// seg1 (2512 blocks): L1 = h1 @ W1b^T (bf16)   (K=256)
// Per K-tile: 4 phases (C-quadrant each).  Staging: chunk p of tile t+1 issued in
// phase p, s_waitcnt vmcnt(6) -> 3 chunks in flight (m201's constant).
// ds_reads fragment-minimal: p0 reads A-half0(8)+B01(4); p1 reads B23(4);
// p2 reads A-half1(8); p3 none.  B held in regs across all 4 phases.
// Epilogue: bf16 stores only (row-sums moved to finalize kernel).
__global__ __launch_bounds__(512, 1) void tails256_kernel(
    const ushort* __restrict__ h0, const ushort* __restrict__ W0b,
    ushort* __restrict__ L0,
    const ushort* __restrict__ h1, const ushort* __restrict__ W1b,
    ushort* __restrict__ L1)
{
    __shared__ ushort lds[2][2][256 * 64];   // 128 KiB

    const int gb = blockIdx.x;
    const ushort *A, *B; ushort* C;
    int K, N, nbx, ldC, lin;
    if (gb < 512) { A = h0; B = W0b; C = L0; K = DH;  N = CC1 - CC0; nbx = N0_P / 256; ldC = N0_P; lin = gb; }
    else          { A = h1; B = W1b; C = L1; K = 256; N = CC2 - CC1; nbx = N1_P / 256; ldC = N1_P; lin = gb - 512; }

    const int nwg = nbx * 16;
    const int q8 = nwg >> 3;
    int bid = (lin & 7) * q8 + (lin >> 3);
    const int by = bid % 16;      // panel-major: consecutive bids share B panel (bx)
    const int bx = bid / 16;
    const int bm = by * 256, bn = bx * 256;

    const int t = threadIdx.x;
    const int lane = t & 63;
    const int w = t >> 6;        // 0..7
    const int wr = w >> 2;       // 0..1  (M half)
    const int wc = w & 3;        // 0..3  (N quarter)
    const int lr = lane & 15;
    const int lg = lane >> 4;
    const int xr = (lr & 7) << 4;          // read-side XOR (bits 4-6)
    const int c0 = w * 64 + lane;          // staging lane id

    f32x4 acc[8][4] = {};
    const int nkt = K / 64;

    // stage chunk p of K-tile `ktile` into buffer `buf`.
    // p: 0 -> A rows {0-63,128-191}; 1 -> B rows {0-31,64-95,128-159,192-223};
    //    2 -> B rows {32-63,96-127,160-191,224-255}; 3 -> A rows {64-127,192-255}
    auto stage_chunk = [&](int ktile, int buf, int p) {
        const int k0 = ktile * 64;
        const int mat = (p == 1 || p == 2) ? 1 : 0;
        const int j = (p == 3) ? 1 : (p == 2 ? 1 : 0);
        const ushort* gbase = mat ? B : A;
        const int brow = mat ? bn : bm;
        #pragma unroll
        for (int i = 0; i < 2; ++i) {
            const int v = i * 512 + c0;       // per-lane virtual index
            const int vrow = v >> 3;          // 0..127 virtual row
            int ar;                           // actual LDS/global row
            if (mat == 0) ar = ((vrow >> 6) << 7) + (j << 6) + (vrow & 63);
            else          ar = ((vrow >> 5) << 6) + (j << 5) + (vrow & 31);
            const int cc = (v & 7) ^ (ar & 7);   // pre-swizzled source col chunk
            const int v0 = (i * 512 + w * 64) >> 3;  // wave-uniform start vrow
            int ar0;
            if (mat == 0) ar0 = ((v0 >> 6) << 7) + (j << 6) + (v0 & 63);
            else          ar0 = ((v0 >> 5) << 6) + (j << 5) + (v0 & 31);
            gload_lds16(gbase + (size_t)(brow + ar) * K + k0 + cc * 8,
                        (char*)&lds[buf][mat][0] + ar0 * 128);
        }
    };

    // ---- prologue: stage tile 0 fully, drain once
    #pragma unroll
    for (int p = 0; p < 4; ++p) stage_chunk(0, 0, p);
    asm volatile("s_waitcnt vmcnt(0)" ::: "memory");
    __builtin_amdgcn_s_barrier();
    asm volatile("" ::: "memory");

    for (int tk = 0; tk < nkt; ++tk) {
        const int cur = tk & 1;
        const char* baseA = (const char*)&lds[cur][0][0];
        const char* baseB = (const char*)&lds[cur][1][0];
        const bool more = (tk + 1 < nkt);

        s16x8 bq[4][2];   // all 4 B fragments, held across phases
        s16x8 af[4][2];   // current A half

        #pragma unroll
        for (int p = 0; p < 4; ++p) {
            const int mh = p >> 1, nh = p & 1;
            // issue chunk p of next tile into the other buffer
            if (more) {
                stage_chunk(tk + 1, cur ^ 1, p);
                asm volatile("s_waitcnt vmcnt(6)" ::: "memory");
            } else {
                if (p == 0)      asm volatile("s_waitcnt vmcnt(4)" ::: "memory");
                else if (p == 1) asm volatile("s_waitcnt vmcnt(2)" ::: "memory");
                else if (p == 2) asm volatile("s_waitcnt vmcnt(0)" ::: "memory");
            }
            __builtin_amdgcn_s_barrier();
            asm volatile("" ::: "memory");

            // fragment-minimal ds_reads
            if (p == 0 || p == 2) {
                #pragma unroll
                for (int m_ = 0; m_ < 4; ++m_) {
                    const int row = wr * 128 + (mh * 4 + m_) * 16 + lr;
                    #pragma unroll
                    for (int ks = 0; ks < 2; ++ks)
                        af[m_][ks] = *(const s16x8*)(baseA + (row * 128 + ((ks * 64 + lg * 16) ^ xr)));
                }
            }
            if (p == 0 || p == 1) {
                #pragma unroll
                for (int n_ = 0; n_ < 2; ++n_) {
                    const int row = wc * 64 + (p * 2 + n_) * 16 + lr;
                    #pragma unroll
                    for (int ks = 0; ks < 2; ++ks)
                        bq[p * 2 + n_][ks] = *(const s16x8*)(baseB + (row * 128 + ((ks * 64 + lg * 16) ^ xr)));
                }
            }
            __builtin_amdgcn_s_setprio(1);
            #pragma unroll
            for (int m_ = 0; m_ < 4; ++m_)
                #pragma unroll
                for (int n_ = 0; n_ < 2; ++n_)
                    #pragma unroll
                    for (int ks = 0; ks < 2; ++ks)
                        acc[mh * 4 + m_][nh * 2 + n_] = __builtin_amdgcn_mfma_f32_16x16x32_bf16(
                            __builtin_bit_cast(bf16x8, af[m_][ks]),
                            __builtin_bit_cast(bf16x8, bq[nh * 2 + n_][ks]),
                            acc[mh * 4 + m_][nh * 2 + n_], 0, 0, 0);
            __builtin_amdgcn_s_setprio(0);
        }
    }

    // ---- epilogue: bf16 stores only
    #pragma unroll
    for (int m = 0; m < 8; ++m) {
        #pragma unroll
        for (int r = 0; r < 4; ++r) {
            const int row = bm + wr * 128 + m * 16 + lg * 4 + r;
            #pragma unroll
            for (int n = 0; n < 4; ++n) {
                const int col = bn + wc * 64 + n * 16 + lr;
                if (col < N)
                    C[(size_t)row * ldC + col] =
                        __builtin_bit_cast(unsigned short, (__bf16)acc[m][n][r]);
            }
        }
    }
}

// ---------------- head log-softmax: one block per row ----------------
__global__ __launch_bounds__(256) void head_lsm_kernel(
    const float* __restrict__ HL, const float* __restrict__ bh,
    float* __restrict__ out, float* __restrict__ s01)
{
    const int row = blockIdx.x;
    const float* L = HL + (size_t)row * OUT_HEAD;
    const int t = threadIdx.x;
    __shared__ float red[4];

    float m = -1e30f;
    for (int i = t; i < OUT_HEAD; i += 256) m = fmaxf(m, L[i] + bh[i]);
    #pragma unroll
    for (int s = 1; s < 64; s <<= 1) m = fmaxf(m, __shfl_xor(m, s, 64));
    if ((t & 63) == 0) red[t >> 6] = m;
    __syncthreads();
    m = fmaxf(fmaxf(red[0], red[1]), fmaxf(red[2], red[3]));

    float sum = 0.f;
    for (int i = t; i < OUT_HEAD; i += 256) sum += __expf(L[i] + bh[i] - m);
    #pragma unroll
    for (int s = 1; s < 64; s <<= 1) sum += __shfl_xor(sum, s, 64);
    __syncthreads();
    if ((t & 63) == 0) red[t >> 6] = sum;
    __syncthreads();
    const float lse = m + logf(red[0] + red[1] + red[2] + red[3]);

    float* orow = out + (size_t)row * CC2;
    for (int i = t; i < CC0; i += 256) orow[i] = L[i] + bh[i] - lse;
    if (t == 0) {
        s01[2 * row + 0] = L[CC0 + 0] + bh[CC0 + 0] - lse;
        s01[2 * row + 1] = L[CC0 + 1] + bh[CC0 + 1] - lse;
    }
}

// ------- finalize: one block per row; pass1 Sum-exp (both tails), pass2 write fp32 ----
__global__ __launch_bounds__(512) void finalize_rows_kernel(
    const ushort* __restrict__ L0, const ushort* __restrict__ L1,
    const float* __restrict__ s01, float* __restrict__ out)
{
    const int row = blockIdx.x;
    const int t = threadIdx.x;
    const ushort* r0 = L0 + (size_t)row * N0_P;
    const ushort* r1 = L1 + (size_t)row * N1_P;

    // pass 1: per-thread partial sums of exp
    float p0 = 0.f, p1 = 0.f;
    for (int c = t; c < 1000; c += 512) {
        s16x8 v = *(const s16x8*)(r0 + c * 8);
        #pragma unroll
        for (int j = 0; j < 8; ++j)
            p0 += __expf(__builtin_bit_cast(float, (unsigned)(unsigned short)v[j] << 16));
    }
    for (int c = t; c < 5000; c += 512) {
        s16x8 v = *(const s16x8*)(r1 + c * 8);
        #pragma unroll
        for (int j = 0; j < 8; ++j)
            p1 += __expf(__builtin_bit_cast(float, (unsigned)(unsigned short)v[j] << 16));
    }
    #pragma unroll
    for (int s = 1; s < 64; s <<= 1) {
        p0 += __shfl_xor(p0, s, 64);
        p1 += __shfl_xor(p1, s, 64);
    }
    __shared__ float red0[8], red1[8], bc[2];
    if ((t & 63) == 0) { red0[t >> 6] = p0; red1[t >> 6] = p1; }
    __syncthreads();
    if (t == 0) {
        float s0 = 0.f, s1 = 0.f;
        #pragma unroll
        for (int i = 0; i < 8; ++i) { s0 += red0[i]; s1 += red1[i]; }
        bc[0] = s01[2 * row + 0] - logf(s0);
        bc[1] = s01[2 * row + 1] - logf(s1);
    }
    __syncthreads();
    const float a0 = bc[0], a1 = bc[1];

    // pass 2: write normalized fp32 (re-reads are L2-resident)
    float* o = out + (size_t)row * CC2;
    for (int c = t; c < 6000; c += 512) {
        const bool t0 = c < 1000;
        const ushort* src = t0 ? r0 + c * 8 : r1 + (size_t)(c - 1000) * 8;
        float* dst = t0 ? o + CC0 + c * 8 : o + CC1 + (c - 1000) * 8;
        const float add = t0 ? a0 : a1;
        s16x8 v = *(const s16x8*)src;
        float4 o0, o1;
        o0.x = __builtin_bit_cast(float, (unsigned)(unsigned short)v[0] << 16) + add;
        o0.y = __builtin_bit_cast(float, (unsigned)(unsigned short)v[1] << 16) + add;
        o0.z = __builtin_bit_cast(float, (unsigned)(unsigned short)v[2] << 16) + add;
        o0.w = __builtin_bit_cast(float, (unsigned)(unsigned short)v[3] << 16) + add;
        o1.x = __builtin_bit_cast(float, (unsigned)(unsigned short)v[4] << 16) + add;
        o1.y = __builtin_bit_cast(float, (unsigned)(unsigned short)v[5] << 16) + add;
        o1.z = __builtin_bit_cast(float, (unsigned)(unsigned short)v[6] << 16) + add;
        o1.w = __builtin_bit_cast(float, (unsigned)(unsigned short)v[7] << 16) + add;
        *(float4*)dst = o0;
        *(float4*)(dst + 4) = o1;
    }
}

// ---------------- launch ----------------
extern "C" void kernel_launch(void* const* d_in, const int* in_sizes, int n_in,
                              void* d_out, int out_size, void* d_ws, size_t ws_size,
                              hipStream_t stream) {
    const float* x   = (const float*)d_in[0];
    const float* Wh  = (const float*)d_in[1];
    const float* bh  = (const float*)d_in[2];
    const float* W0a = (const float*)d_in[3];
    const float* W0b = (const float*)d_in[4];
    const float* W1a = (const float*)d_in[5];
    const float* W1b = (const float*)d_in[6];
    float* out = (float*)d_out;
    char*  ws  = (char*)d_ws;

    size_t off = 0;
    auto alloc = [&](size_t bytes) { size_t o = off; off += (bytes + 255) & ~(size_t)255; return o; };
    ushort* x_bf   = (ushort*)(ws + alloc((size_t)BATCH * DH * 2));
    ushort* Wh_bf  = (ushort*)(ws + alloc((size_t)NH_P * DH * 2));
    ushort* W0a_bf = (ushort*)(ws + alloc((size_t)DH * DH * 2));
    ushort* W0b_bf = (ushort*)(ws + alloc((size_t)N0_P * DH * 2));
    ushort* W1a_bf = (ushort*)(ws + alloc((size_t)256 * DH * 2));
    ushort* W1b_bf = (ushort*)(ws + alloc((size_t)N1_P * 256 * 2));
    ushort* h0_bf  = (ushort*)(ws + alloc((size_t)BATCH * DH * 2));
    ushort* h1_bf  = (ushort*)(ws + alloc((size_t)BATCH * 256 * 2));
    float*  headL  = (float*)(ws + alloc((size_t)BATCH * OUT_HEAD * 4));
    float*  s01    = (float*)(ws + alloc((size_t)BATCH * 2 * 4));
    ushort* L0     = (ushort*)(ws + alloc((size_t)BATCH * N0_P * 2));
    ushort* L1     = (ushort*)(ws + alloc((size_t)BATCH * N1_P * 2));

    convert_all_kernel<<<dim3(1280, 6), 256, 0, stream>>>(
        (const float4*)x,   (ushort4*)x_bf,   BATCH * DH / 4,        BATCH * DH / 4,
        (const float4*)Wh,  (ushort4*)Wh_bf,  OUT_HEAD * DH / 4,     NH_P * DH / 4,
        (const float4*)W0a, (ushort4*)W0a_bf, DH * DH / 4,           DH * DH / 4,
        (const float4*)W0b, (ushort4*)W0b_bf, (CC1 - CC0) * DH / 4,  N0_P * DH / 4,
        (const float4*)W1a, (ushort4*)W1a_bf, 256 * DH / 4,          256 * DH / 4,
        (const float4*)W1b, (ushort4*)W1b_bf, (CC2 - CC1) * 256 / 4, N1_P * 256 / 4);

    // producers: h0 (256 blocks) + h1 (64) + head (512)
    gemm128x3_kernel<<<832, 256, 0, stream>>>(
        x_bf, W0a_bf, h0_bf, W1a_bf, h1_bf, Wh_bf, headL);

    // head log-softmax -> out[:, :2000] + cluster scalars
    head_lsm_kernel<<<BATCH, 256, 0, stream>>>(headL, bh, out, s01);

    // fused tails: bf16 logits (no rowsum work in epilogue)
    tails256_kernel<<<512 + (N1_P / 256) * 16, 512, 0, stream>>>(
        h0_bf, W0b_bf, L0, h1_bf, W1b_bf, L1);

    // finalize: per-row Sum-exp + normalized fp32 write
    finalize_rows_kernel<<<BATCH, 512, 0, stream>>>(L0, L1, s01, out);
}